// Round 2
// baseline (455.289 us; speedup 1.0000x reference)
//
#include <hip/hip_runtime.h>

// Problem: B=32, C=2048, Q=128, E=200. Inputs fp32, OUTPUT fp32 (B,C,4E).
#define B_ 32
#define C_ 2048
#define Q_ 128
#define E_ 200
#define TB 32    // c-rows per block in row2_kernel

typedef __attribute__((ext_vector_type(4))) float f32x4;

// ---------------------------------------------------------------- K0
// xqT[b][e][q] = xq[b][q][e]  via padded-LDS 32x32 tile (coalesced both sides)
__global__ __launch_bounds__(256) void xqt_kernel(const float* __restrict__ xq,
                                                  float* __restrict__ xqT) {
    __shared__ float tl[32][33];
    const int blk = blockIdx.x;               // B * 4 * 7 = 896
    const int b  = blk / 28;
    const int r  = blk - b * 28;
    const int qt = r / 7, et = r - (r / 7) * 7;
    const int q0 = qt * 32, e0 = et * 32;
    const int tx = threadIdx.x & 31, ty = threadIdx.x >> 5;   // 32 x 8
    #pragma unroll
    for (int i = 0; i < 4; ++i) {
        const int q = q0 + ty + 8 * i, e = e0 + tx;
        if (e < E_) tl[ty + 8 * i][tx] = xq[((size_t)b * Q_ + q) * E_ + e];
    }
    __syncthreads();
    #pragma unroll
    for (int i = 0; i < 4; ++i) {
        const int e = e0 + ty + 8 * i, q = q0 + tx;
        if (e < E_) xqT[((size_t)b * E_ + e) * Q_ + q] = tl[tx][ty + 8 * i];
    }
}

// ---------------------------------------------------------------- K1
// s_q[b,q] = dot(x_q[b,q,:], w2) — coalesced via xqT
__global__ __launch_bounds__(128) void sq_kernel(const float* __restrict__ xqT,
                                                 const float* __restrict__ w,
                                                 float* __restrict__ sq) {
    const int b = blockIdx.x, q = threadIdx.x;
    const float* base = xqT + (size_t)b * E_ * Q_ + q;
    float a = 0.f;
    #pragma unroll 8
    for (int e = 0; e < E_; ++e) a = fmaf(base[e * Q_], w[E_ + e], a);
    sq[b * Q_ + q] = a;
}

// ---------------------------------------------------------------- K2
// One block per 32 c-rows of one b. 256 threads = 8 c-groups x 32 q-groups,
// each thread owns a 4c x 4q register tile. Softmax fully in registers.
// LDS: scw3 (phase 0-1) and P (phase 2-3) ALIAS the same buffer -> 25.7 KB,
// occupancy limiter moves to VGPR (16 waves/CU vs 12 before).
__global__ __launch_bounds__(256) void row2_kernel(const float* __restrict__ xc_g,
                                                   const float* __restrict__ xq_g,
                                                   const float* __restrict__ xqT_g,
                                                   const float* __restrict__ w_g,
                                                   const float* __restrict__ sq_g,
                                                   float* __restrict__ m_g,
                                                   float* __restrict__ out) {
    __shared__ float buf[TB][E_];      // 25.6 KB: scw3 rows, then P rows (cols 0..127)
    __shared__ float sc_l[TB];

    const int t = threadIdx.x;
    // XCD-aware mapping: all 64 tiles of a b share blk%8 -> same XCD L2.
    const int blk = blockIdx.x;                 // 0..2047
    const int x   = blk & 7;
    const int g   = blk >> 3;                   // 0..255
    const int b   = x * 4 + (g >> 6);
    const int tile = g & 63;
    const int bc0 = b * C_ + tile * TB;

    // ---- phase 0: stage scw3 rows; s_c = xc.w1 (8 lanes per row) ----
    {
        const int r  = t >> 3;               // 0..31
        const int k  = t & 7;                // 0..7
        const int e0 = k * 25;
        const float* xc_row = xc_g + (size_t)(bc0 + r) * E_;
        float p1 = 0.f;
        #pragma unroll
        for (int i = 0; i < 25; ++i) {
            const int e = e0 + i;
            const float v = xc_row[e];
            buf[r][e] = v * w_g[2 * E_ + e];
            p1 = fmaf(v, w_g[e], p1);
        }
        p1 += __shfl_xor(p1, 1);
        p1 += __shfl_xor(p1, 2);
        p1 += __shfl_xor(p1, 4);
        if (k == 0) sc_l[r] = p1;
    }
    __syncthreads();                         // (A) scw3 + sc_l visible

    const int qg = t & 31;
    const int cg = t >> 5;                   // 0..7
    const int c4 = cg * 4;
    const int q4 = qg * 4;

    // ---- phase 1: S[4c][4q] = scw3_tile @ xqT  (xqT reads lane-coalesced) ----
    f32x4 acc[4] = {};
    const float* xqT_b = xqT_g + (size_t)b * E_ * Q_;
    #pragma unroll 2
    for (int e = 0; e < E_; e += 4) {
        const f32x4 x0 = *(const f32x4*)&xqT_b[(e + 0) * Q_ + q4];
        const f32x4 x1 = *(const f32x4*)&xqT_b[(e + 1) * Q_ + q4];
        const f32x4 x2 = *(const f32x4*)&xqT_b[(e + 2) * Q_ + q4];
        const f32x4 x3 = *(const f32x4*)&xqT_b[(e + 3) * Q_ + q4];
        #pragma unroll
        for (int ci = 0; ci < 4; ++ci) {
            const f32x4 a = *(const f32x4*)&buf[c4 + ci][e];   // broadcast: free
            acc[ci] += a.x * x0 + a.y * x1 + a.z * x2 + a.w * x3;
        }
    }
    __syncthreads();                         // (B) all scw3 reads done (buf reuse)

    // ---- phase 2: in-register softmax over q (reduce across the 32-lane q-group) ----
    const f32x4 sqv = *(const f32x4*)&sq_g[b * Q_ + q4];
    float mx[4], sm[4];
    #pragma unroll
    for (int ci = 0; ci < 4; ++ci) {
        acc[ci] += sc_l[c4 + ci] + sqv;
        mx[ci] = fmaxf(fmaxf(acc[ci].x, acc[ci].y), fmaxf(acc[ci].z, acc[ci].w));
    }
    #pragma unroll
    for (int off = 16; off; off >>= 1) {
        #pragma unroll
        for (int ci = 0; ci < 4; ++ci) mx[ci] = fmaxf(mx[ci], __shfl_xor(mx[ci], off));
    }
    if (qg == 0) {
        #pragma unroll
        for (int ci = 0; ci < 4; ++ci) m_g[bc0 + c4 + ci] = mx[ci];
    }
    #pragma unroll
    for (int ci = 0; ci < 4; ++ci) {
        f32x4 p;
        p.x = __expf(acc[ci].x - mx[ci]);
        p.y = __expf(acc[ci].y - mx[ci]);
        p.z = __expf(acc[ci].z - mx[ci]);
        p.w = __expf(acc[ci].w - mx[ci]);
        acc[ci] = p;
        sm[ci] = (p.x + p.y) + (p.z + p.w);
    }
    #pragma unroll
    for (int off = 16; off; off >>= 1) {
        #pragma unroll
        for (int ci = 0; ci < 4; ++ci) sm[ci] += __shfl_xor(sm[ci], off);
    }
    #pragma unroll
    for (int ci = 0; ci < 4; ++ci) {
        acc[ci] *= (1.f / sm[ci]);
        *(f32x4*)&buf[c4 + ci][q4] = acc[ci];   // P (normalized), aliases scw3
    }
    __syncthreads();                         // (C) P visible

    // ---- phase 3: c2q = P @ xq (xq reads lane-coalesced along e) + epilogue ----
    const float* xq_b = xq_g + (size_t)b * Q_ * E_;
    #pragma unroll
    for (int pass = 0; pass < 2; ++pass) {
        const int e4 = pass * 128 + q4;          // pass1: lanes with e4 >= 200 idle
        if (e4 < E_) {
            f32x4 o[4] = {};
            for (int q = 0; q < Q_; q += 4) {
                const f32x4 xv0 = *(const f32x4*)&xq_b[(q + 0) * E_ + e4];
                const f32x4 xv1 = *(const f32x4*)&xq_b[(q + 1) * E_ + e4];
                const f32x4 xv2 = *(const f32x4*)&xq_b[(q + 2) * E_ + e4];
                const f32x4 xv3 = *(const f32x4*)&xq_b[(q + 3) * E_ + e4];
                #pragma unroll
                for (int ci = 0; ci < 4; ++ci) {
                    const f32x4 p = *(const f32x4*)&buf[c4 + ci][q];  // broadcast
                    o[ci] += p.x * xv0 + p.y * xv1 + p.z * xv2 + p.w * xv3;
                }
            }
            #pragma unroll
            for (int ci = 0; ci < 4; ++ci) {
                const size_t row = (size_t)(bc0 + c4 + ci);
                const f32x4 xcv = *(const f32x4*)&xc_g[row * E_ + e4];
                float* orow = out + row * (4 * E_);
                *(f32x4*)&orow[e4]          = xcv;
                *(f32x4*)&orow[E_ + e4]     = o[ci];
                *(f32x4*)&orow[2 * E_ + e4] = xcv * o[ci];
            }
        }
    }
}

// ---------------------------------------------------------------- K3
// per-b max & denominator over m[b, 0:C]
__global__ __launch_bounds__(256) void stats_kernel(const float* __restrict__ m_g,
                                                    float* __restrict__ bstat) {
    __shared__ float red[4];
    const int b = blockIdx.x, t = threadIdx.x;
    float mx = -3.4e38f;
    for (int c = t; c < C_; c += 256) mx = fmaxf(mx, m_g[b * C_ + c]);
    #pragma unroll
    for (int off = 32; off; off >>= 1) mx = fmaxf(mx, __shfl_xor(mx, off));
    if ((t & 63) == 0) red[t >> 6] = mx;
    __syncthreads();
    mx = fmaxf(fmaxf(red[0], red[1]), fmaxf(red[2], red[3]));
    __syncthreads();
    float sum = 0.f;
    for (int c = t; c < C_; c += 256) sum += __expf(m_g[b * C_ + c] - mx);
    #pragma unroll
    for (int off = 32; off; off >>= 1) sum += __shfl_xor(sum, off);
    if ((t & 63) == 0) red[t >> 6] = sum;
    __syncthreads();
    if (t == 0) {
        bstat[b]      = mx;
        bstat[B_ + b] = red[0] + red[1] + red[2] + red[3];
    }
}

// ---------------------------------------------------------------- K4a
// partial q2c over a 128-c chunk: part[b*16+g][e]  (XCD-grouped by b)
__global__ __launch_bounds__(256) void q2c_partial(const float* __restrict__ xc_g,
                                                   const float* __restrict__ m_g,
                                                   const float* __restrict__ bstat,
                                                   float* __restrict__ part) {
    __shared__ float wl[128];
    const int blk = blockIdx.x;               // 0..511
    const int x = blk & 7, u = blk >> 3;      // u: 0..63
    const int b = x * 4 + (u >> 4), g = u & 15;
    const int t = threadIdx.x;
    const float mx  = bstat[b];
    const float inv = 1.f / bstat[B_ + b];
    if (t < 128) wl[t] = __expf(m_g[b * C_ + g * 128 + t] - mx) * inv;
    __syncthreads();
    if (t < E_) {
        float acc = 0.f;
        const float* base = xc_g + ((size_t)(b * C_ + g * 128)) * E_ + t;
        #pragma unroll 8
        for (int c = 0; c < 128; ++c) acc = fmaf(wl[c], base[(size_t)c * E_], acc);
        part[(size_t)(b * 16 + g) * E_ + t] = acc;
    }
}

// ---------------------------------------------------------------- K4b
__global__ __launch_bounds__(256) void q2c_reduce(const float* __restrict__ part,
                                                  float* __restrict__ q2c) {
    const int b = blockIdx.x, t = threadIdx.x;
    if (t < E_) {
        float a = 0.f;
        #pragma unroll
        for (int g = 0; g < 16; ++g) a += part[(size_t)(b * 16 + g) * E_ + t];
        q2c[b * E_ + t] = a;
    }
}

// ---------------------------------------------------------------- K5
// out[..., 3E:4E] = x_c * q2c (broadcast over c), f32x4 vectorized
__global__ __launch_bounds__(256) void out4_kernel(const float* __restrict__ xc_g,
                                                   const float* __restrict__ q2c,
                                                   float* __restrict__ out) {
    const unsigned int idx = blockIdx.x * 256u + threadIdx.x;  // < B*C*E/4
    const unsigned int n = idx * 4u;
    const unsigned int e = n % E_;              // multiple of 4, same row for all 4
    const unsigned int row = n / E_;            // b*C + c
    const unsigned int b = row / C_;
    const f32x4 xcv = *(const f32x4*)&xc_g[n];
    const f32x4 qv  = *(const f32x4*)&q2c[b * E_ + e];
    *(f32x4*)&out[(size_t)row * (4 * E_) + 3 * E_ + e] = xcv * qv;
}

extern "C" void kernel_launch(void* const* d_in, const int* in_sizes, int n_in,
                              void* d_out, int out_size, void* d_ws, size_t ws_size,
                              hipStream_t stream) {
    // order-robust input selection by element count
    const float* xc = (const float*)d_in[0];
    const float* xq = (const float*)d_in[1];
    const float* w  = (const float*)d_in[2];
    for (int i = 0; i < n_in; ++i) {
        if      (in_sizes[i] == B_ * C_ * E_) xc = (const float*)d_in[i];
        else if (in_sizes[i] == B_ * Q_ * E_) xq = (const float*)d_in[i];
        else if (in_sizes[i] == 3 * E_)       w  = (const float*)d_in[i];
    }
    float* out = (float*)d_out;

    float* ws    = (float*)d_ws;
    float* sq    = ws;                 // B*Q   = 4096
    float* m     = sq + B_ * Q_;       // B*C   = 65536
    float* bstat = m + B_ * C_;        // 2*B   = 64
    float* q2c   = bstat + 2 * B_;     // B*E   = 6400
    float* xqT   = q2c + B_ * E_;      // B*E*Q = 819200  (~3.3 MB)
    float* part  = xqT;                // reused AFTER row2 completes (stream-ordered)

    xqt_kernel  <<<B_ * 28,         256, 0, stream>>>(xq, xqT);
    sq_kernel   <<<B_,              128, 0, stream>>>(xqT, w, sq);
    row2_kernel <<<B_ * (C_ / TB),  256, 0, stream>>>(xc, xq, xqT, w, sq, m, out);
    stats_kernel<<<B_,              256, 0, stream>>>(m, bstat);
    q2c_partial <<<B_ * 16,         256, 0, stream>>>(xc, m, bstat, part);
    q2c_reduce  <<<B_,              256, 0, stream>>>(part, q2c);
    out4_kernel <<<(B_ * C_ * E_ / 4) / 256, 256, 0, stream>>>(xc, q2c, out);
}

// Round 3
// 407.584 us; speedup vs baseline: 1.1170x; 1.1170x over previous
//
#include <hip/hip_runtime.h>

// Problem: B=32, C=2048, Q=128, E=200. Inputs fp32, OUTPUT fp32 (B,C,4E).
// R2 post-mortem: XCD swizzle + LDS aliasing in row2 REGRESSED (171->221us):
//   occupancy never rose (30% flat), extra barrier cost +50us stall.
//   row2 below is the exact R1 version (measured 171us).
#define B_ 32
#define C_ 2048
#define Q_ 128
#define E_ 200
#define TB 32    // c-rows per block in row2_kernel

typedef __attribute__((ext_vector_type(4))) float f32x4;

// ---------------------------------------------------------------- K0
// xqT[b][e][q] = xq[b][q][e]  via padded-LDS 32x32 tile (coalesced both sides)
__global__ __launch_bounds__(256) void xqt_kernel(const float* __restrict__ xq,
                                                  float* __restrict__ xqT) {
    __shared__ float tl[32][33];
    const int blk = blockIdx.x;               // B * 4 * 7 = 896
    const int b  = blk / 28;
    const int r  = blk - b * 28;
    const int qt = r / 7, et = r - (r / 7) * 7;
    const int q0 = qt * 32, e0 = et * 32;
    const int tx = threadIdx.x & 31, ty = threadIdx.x >> 5;   // 32 x 8
    #pragma unroll
    for (int i = 0; i < 4; ++i) {
        const int q = q0 + ty + 8 * i, e = e0 + tx;
        if (e < E_) tl[ty + 8 * i][tx] = xq[((size_t)b * Q_ + q) * E_ + e];
    }
    __syncthreads();
    #pragma unroll
    for (int i = 0; i < 4; ++i) {
        const int e = e0 + ty + 8 * i, q = q0 + tx;
        if (e < E_) xqT[((size_t)b * E_ + e) * Q_ + q] = tl[tx][ty + 8 * i];
    }
}

// ---------------------------------------------------------------- K1
// s_q[b,q] = dot(x_q[b,q,:], w2). One WAVE per q-row, coalesced f32x4 loads.
__global__ __launch_bounds__(256) void sq_kernel(const float* __restrict__ xq,
                                                 const float* __restrict__ w,
                                                 float* __restrict__ sq) {
    const int wave = blockIdx.x * 4 + (threadIdx.x >> 6);  // 0..B*Q-1
    const int lane = threadIdx.x & 63;
    const float* row = xq + (size_t)wave * E_;
    float a = 0.f;
    if (lane < 50) {                                        // 50*4 = 200 = E_
        const f32x4 v  = *(const f32x4*)&row[lane * 4];
        const f32x4 wv = *(const f32x4*)&w[E_ + lane * 4];
        a = (v.x * wv.x + v.y * wv.y) + (v.z * wv.z + v.w * wv.w);
    }
    #pragma unroll
    for (int off = 32; off; off >>= 1) a += __shfl_xor(a, off);
    if (lane == 0) sq[wave] = a;
}

// ---------------------------------------------------------------- K2  (exact R1)
// One block per 32 c-rows of one b. 256 threads = 8 c-groups x 32 q-groups,
// each thread owns a 4c x 4q register tile. Softmax fully in registers.
__global__ __launch_bounds__(256) void row2_kernel(const float* __restrict__ xc_g,
                                                   const float* __restrict__ xq_g,
                                                   const float* __restrict__ xqT_g,
                                                   const float* __restrict__ w_g,
                                                   const float* __restrict__ sq_g,
                                                   float* __restrict__ m_g,
                                                   float* __restrict__ out) {
    __shared__ float scw3_l[TB][E_];   // 25.6 KB  (xc*w3)
    __shared__ float P_l[TB][Q_];      // 16.0 KB  (normalized softmax probs)
    __shared__ float sc_l[TB];

    const int t    = threadIdx.x;
    const int b    = blockIdx.x >> 6;        // C_/TB = 64 tiles per b
    const int tile = blockIdx.x & 63;
    const int bc0  = b * C_ + tile * TB;

    // ---- phase 0: stage scw3 rows; s_c = xc.w1 (8 lanes per row) ----
    {
        const int r  = t >> 3;               // 0..31
        const int k  = t & 7;                // 0..7
        const int e0 = k * 25;
        const float* xc_row = xc_g + (size_t)(bc0 + r) * E_;
        float p1 = 0.f;
        #pragma unroll
        for (int i = 0; i < 25; ++i) {
            const int e = e0 + i;
            const float v = xc_row[e];
            scw3_l[r][e] = v * w_g[2 * E_ + e];
            p1 = fmaf(v, w_g[e], p1);
        }
        p1 += __shfl_xor(p1, 1);
        p1 += __shfl_xor(p1, 2);
        p1 += __shfl_xor(p1, 4);
        if (k == 0) sc_l[r] = p1;
    }
    __syncthreads();

    const int qg = t & 31;
    const int cg = t >> 5;                   // 0..7
    const int c4 = cg * 4;
    const int q4 = qg * 4;

    // ---- phase 1: S[4c][4q] = scw3_tile @ xqT  (xqT reads lane-coalesced) ----
    f32x4 acc[4] = {};
    const float* xqT_b = xqT_g + (size_t)b * E_ * Q_;
    for (int e = 0; e < E_; e += 4) {
        const f32x4 x0 = *(const f32x4*)&xqT_b[(e + 0) * Q_ + q4];
        const f32x4 x1 = *(const f32x4*)&xqT_b[(e + 1) * Q_ + q4];
        const f32x4 x2 = *(const f32x4*)&xqT_b[(e + 2) * Q_ + q4];
        const f32x4 x3 = *(const f32x4*)&xqT_b[(e + 3) * Q_ + q4];
        #pragma unroll
        for (int ci = 0; ci < 4; ++ci) {
            const f32x4 a = *(const f32x4*)&scw3_l[c4 + ci][e];  // broadcast: free
            acc[ci] += a.x * x0 + a.y * x1 + a.z * x2 + a.w * x3;
        }
    }

    // ---- phase 2: in-register softmax over q (reduce across the 32-lane q-group) ----
    const f32x4 sqv = *(const f32x4*)&sq_g[b * Q_ + q4];
    float mx[4], sm[4];
    #pragma unroll
    for (int ci = 0; ci < 4; ++ci) {
        acc[ci] += sc_l[c4 + ci] + sqv;
        mx[ci] = fmaxf(fmaxf(acc[ci].x, acc[ci].y), fmaxf(acc[ci].z, acc[ci].w));
    }
    #pragma unroll
    for (int off = 16; off; off >>= 1) {
        #pragma unroll
        for (int ci = 0; ci < 4; ++ci) mx[ci] = fmaxf(mx[ci], __shfl_xor(mx[ci], off));
    }
    if (qg == 0) {
        #pragma unroll
        for (int ci = 0; ci < 4; ++ci) m_g[bc0 + c4 + ci] = mx[ci];
    }
    #pragma unroll
    for (int ci = 0; ci < 4; ++ci) {
        f32x4 p;
        p.x = __expf(acc[ci].x - mx[ci]);
        p.y = __expf(acc[ci].y - mx[ci]);
        p.z = __expf(acc[ci].z - mx[ci]);
        p.w = __expf(acc[ci].w - mx[ci]);
        acc[ci] = p;
        sm[ci] = (p.x + p.y) + (p.z + p.w);
    }
    #pragma unroll
    for (int off = 16; off; off >>= 1) {
        #pragma unroll
        for (int ci = 0; ci < 4; ++ci) sm[ci] += __shfl_xor(sm[ci], off);
    }
    #pragma unroll
    for (int ci = 0; ci < 4; ++ci) {
        acc[ci] *= (1.f / sm[ci]);
        *(f32x4*)&P_l[c4 + ci][q4] = acc[ci];   // normalized probs
    }
    __syncthreads();

    // ---- phase 3: c2q = P @ xq (xq reads lane-coalesced along e) + epilogue ----
    const float* xq_b = xq_g + (size_t)b * Q_ * E_;
    #pragma unroll
    for (int pass = 0; pass < 2; ++pass) {
        const int e4 = pass * 128 + q4;          // pass1: lanes with e4 >= 200 idle
        if (e4 < E_) {
            f32x4 o[4] = {};
            for (int q = 0; q < Q_; q += 4) {
                const f32x4 xv0 = *(const f32x4*)&xq_b[(q + 0) * E_ + e4];
                const f32x4 xv1 = *(const f32x4*)&xq_b[(q + 1) * E_ + e4];
                const f32x4 xv2 = *(const f32x4*)&xq_b[(q + 2) * E_ + e4];
                const f32x4 xv3 = *(const f32x4*)&xq_b[(q + 3) * E_ + e4];
                #pragma unroll
                for (int ci = 0; ci < 4; ++ci) {
                    const f32x4 p = *(const f32x4*)&P_l[c4 + ci][q];  // broadcast
                    o[ci] += p.x * xv0 + p.y * xv1 + p.z * xv2 + p.w * xv3;
                }
            }
            #pragma unroll
            for (int ci = 0; ci < 4; ++ci) {
                const size_t row = (size_t)(bc0 + c4 + ci);
                const f32x4 xcv = *(const f32x4*)&xc_g[row * E_ + e4];
                float* orow = out + row * (4 * E_);
                *(f32x4*)&orow[e4]          = xcv;
                *(f32x4*)&orow[E_ + e4]     = o[ci];
                *(f32x4*)&orow[2 * E_ + e4] = xcv * o[ci];
            }
        }
    }
}

// ---------------------------------------------------------------- K4a
// Online-max partial q2c over a 64-c chunk (stats kernel eliminated).
// part[blk][e] = sum_c exp(m[c]-mxloc)*xc[c][e];  pmax/psum per chunk.
__global__ __launch_bounds__(256) void q2c_partial(const float* __restrict__ xc_g,
                                                   const float* __restrict__ m_g,
                                                   float* __restrict__ part,
                                                   float* __restrict__ pmax,
                                                   float* __restrict__ psum) {
    __shared__ float wl[64];
    __shared__ float red;
    const int blk = blockIdx.x;               // 0..B*32-1
    const int b = blk >> 5, g = blk & 31;     // 32 chunks of 64 c per b
    const int t = threadIdx.x;
    const int c0 = g * 64;

    const float v = (t < 64) ? m_g[b * C_ + c0 + t] : -3.4e38f;
    if (t < 64) {                              // wave 0 only
        float mxl = v;
        #pragma unroll
        for (int off = 32; off; off >>= 1) mxl = fmaxf(mxl, __shfl_xor(mxl, off));
        const float e = __expf(v - mxl);
        wl[t] = e;
        float s = e;
        #pragma unroll
        for (int off = 32; off; off >>= 1) s += __shfl_xor(s, off);
        if (t == 0) { pmax[blk] = mxl; psum[blk] = s; red = mxl; }
    }
    __syncthreads();

    if (t < E_) {
        float acc = 0.f;
        const float* base = xc_g + ((size_t)(b * C_ + c0)) * E_ + t;
        #pragma unroll 8
        for (int c = 0; c < 64; ++c) acc = fmaf(wl[c], base[(size_t)c * E_], acc);
        part[(size_t)blk * E_ + t] = acc;
    }
}

// ---------------------------------------------------------------- K4b
// Combine 32 chunks: global max M, total = sum psum*exp(pmax-M),
// q2c[e] = sum part*exp(pmax-M) / total
__global__ __launch_bounds__(256) void q2c_reduce(const float* __restrict__ part,
                                                  const float* __restrict__ pmax,
                                                  const float* __restrict__ psum,
                                                  float* __restrict__ q2c) {
    __shared__ float sc[32];
    __shared__ float inv_total;
    const int b = blockIdx.x, t = threadIdx.x;
    if (t < 64) {                              // wave 0
        const float pm = (t < 32) ? pmax[b * 32 + t] : -3.4e38f;
        float M = pm;
        #pragma unroll
        for (int off = 32; off; off >>= 1) M = fmaxf(M, __shfl_xor(M, off));
        const float s = (t < 32) ? __expf(pm - M) : 0.f;
        float tot = (t < 32) ? psum[b * 32 + t] * s : 0.f;
        #pragma unroll
        for (int off = 32; off; off >>= 1) tot += __shfl_xor(tot, off);
        if (t < 32) sc[t] = s;
        if (t == 0) inv_total = 1.f / tot;
    }
    __syncthreads();
    if (t < E_) {
        float a = 0.f;
        #pragma unroll
        for (int g = 0; g < 32; ++g)
            a = fmaf(part[(size_t)(b * 32 + g) * E_ + t], sc[g], a);
        q2c[b * E_ + t] = a * inv_total;
    }
}

// ---------------------------------------------------------------- K5
// out[..., 3E:4E] = x_c * q2c (broadcast over c), f32x4 vectorized
__global__ __launch_bounds__(256) void out4_kernel(const float* __restrict__ xc_g,
                                                   const float* __restrict__ q2c,
                                                   float* __restrict__ out) {
    const unsigned int idx = blockIdx.x * 256u + threadIdx.x;  // < B*C*E/4
    const unsigned int n = idx * 4u;
    const unsigned int e = n % E_;              // multiple of 4, same row for all 4
    const unsigned int row = n / E_;            // b*C + c
    const unsigned int b = row / C_;
    const f32x4 xcv = *(const f32x4*)&xc_g[n];
    const f32x4 qv  = *(const f32x4*)&q2c[b * E_ + e];
    *(f32x4*)&out[(size_t)row * (4 * E_) + 3 * E_ + e] = xcv * qv;
}

extern "C" void kernel_launch(void* const* d_in, const int* in_sizes, int n_in,
                              void* d_out, int out_size, void* d_ws, size_t ws_size,
                              hipStream_t stream) {
    // order-robust input selection by element count
    const float* xc = (const float*)d_in[0];
    const float* xq = (const float*)d_in[1];
    const float* w  = (const float*)d_in[2];
    for (int i = 0; i < n_in; ++i) {
        if      (in_sizes[i] == B_ * C_ * E_) xc = (const float*)d_in[i];
        else if (in_sizes[i] == B_ * Q_ * E_) xq = (const float*)d_in[i];
        else if (in_sizes[i] == 3 * E_)       w  = (const float*)d_in[i];
    }
    float* out = (float*)d_out;

    float* ws    = (float*)d_ws;
    float* sq    = ws;                 // B*Q   = 4096
    float* m     = sq + B_ * Q_;       // B*C   = 65536
    float* q2c   = m + B_ * C_;        // B*E   = 6400
    float* xqT   = q2c + B_ * E_;      // B*E*Q = 819200  (~3.3 MB)
    // part/pmax/psum alias xqT: written only AFTER row2 (stream-ordered), and
    // 1024*200 + 2*1024 = 206848 floats fits well inside xqT's 819200.
    float* part  = xqT;                            // [B*32][E_]
    float* pmax  = xqT + 262144;                   // [B*32]
    float* psum  = xqT + 262144 + 2048;            // [B*32]

    xqt_kernel  <<<B_ * 28,            256, 0, stream>>>(xq, xqT);
    sq_kernel   <<<B_ * Q_ / 4,        256, 0, stream>>>(xq, w, sq);
    row2_kernel <<<B_ * (C_ / TB),     256, 0, stream>>>(xc, xq, xqT, w, sq, m, out);
    q2c_partial <<<B_ * 32,            256, 0, stream>>>(xc, m, part, pmax, psum);
    q2c_reduce  <<<B_,                 256, 0, stream>>>(part, pmax, psum, q2c);
    out4_kernel <<<(B_ * C_ * E_ / 4) / 256, 256, 0, stream>>>(xc, q2c, out);
}